// Round 2
// baseline (1179.990 us; speedup 1.0000x reference)
//
#include <hip/hip_runtime.h>

#define B_ 128
#define T_ 1024
#define I_ 128
#define H_ 256
#define O_ 64

// ---------------------------------------------------------------------------
// Phase A: xw[row, j] = sum_i x[row, i] * W_xh[j, i] + b_h[j]
// 512 WGs x 256 threads (2 WG/CU). Thread tid owns column j = tid with the
// full K=128 weight row in registers (32 float4). x staged 8 rows/tile into
// LDS (double-buffered), read as wave-broadcasts. No reduction phase,
// 1 barrier per 8 rows.
// ---------------------------------------------------------------------------
__global__ __launch_bounds__(256, 2)
void xw_gemm_kernel(const float* __restrict__ x, const float* __restrict__ W_xh,
                    const float* __restrict__ b_h, float* __restrict__ xw)
{
    const int tid = threadIdx.x;
    __shared__ __align__(16) float xs[2][8 * I_];     // 2 x 4 KB

    float4 w[32];
    {
        const float4* wp = reinterpret_cast<const float4*>(W_xh + (size_t)tid * I_);
#pragma unroll
        for (int c4 = 0; c4 < 32; ++c4) w[c4] = wp[c4];
    }
    const float bh = b_h[tid];

    const int rowsPerWG = (B_ * T_) / 512;            // 256
    const int base = blockIdx.x * rowsPerWG;
    const int ntiles = rowsPerWG / 8;                 // 32

    // stage tile 0: 8 rows x 128 floats = 4 KB = 256 threads x 1 float4
    {
        const float4* xp = reinterpret_cast<const float4*>(x + (size_t)base * I_);
        reinterpret_cast<float4*>(xs[0])[tid] = xp[tid];
    }
    __syncthreads();

    int buf = 0;
    for (int tb = 0; tb < ntiles; ++tb) {
        float4 xnext = make_float4(0.f, 0.f, 0.f, 0.f);
        if (tb + 1 < ntiles) {                        // issue prefetch early
            const float4* xp = reinterpret_cast<const float4*>(
                x + (size_t)(base + (tb + 1) * 8) * I_);
            xnext = xp[tid];
        }

        float acc[8];
#pragma unroll
        for (int r = 0; r < 8; ++r) acc[r] = 0.f;
        const float4* xb = reinterpret_cast<const float4*>(xs[buf]);
#pragma unroll 4
        for (int c4 = 0; c4 < 32; ++c4) {
            const float4 wv = w[c4];
#pragma unroll
            for (int r = 0; r < 8; ++r) {
                const float4 xv = xb[r * 32 + c4];    // wave-broadcast LDS read
                acc[r] = fmaf(xv.x, wv.x, acc[r]);
                acc[r] = fmaf(xv.y, wv.y, acc[r]);
                acc[r] = fmaf(xv.z, wv.z, acc[r]);
                acc[r] = fmaf(xv.w, wv.w, acc[r]);
            }
        }
        {
            float* orow = xw + (size_t)(base + tb * 8) * H_ + tid;
#pragma unroll
            for (int r = 0; r < 8; ++r) orow[(size_t)r * H_] = acc[r] + bh;
        }
        if (tb + 1 < ntiles)
            reinterpret_cast<float4*>(xs[buf ^ 1])[tid] = xnext;
        __syncthreads();
        buf ^= 1;
    }
}

// ---------------------------------------------------------------------------
// Phase B: fused recurrence + output projection, 2 barriers/step.
// One WG (512 thr) per batch row; W_hh register-resident (128 VGPR/lane),
// W_out register-resident (32 VGPR/lane).
//   phase 1 (all 8 waves): recurrence fmacs for h_t -> part;
//                          out-proj fmacs on h_{t-1} -> opart
//   barrier
//   phase 2: waves 0-3 reduce part(+xw,relu) -> hs;
//            wave 4 reduces opart -> global store out_{t-1}   (concurrent)
//   barrier
//   all: hr <- hs   (registers for next step)
// Iteration 0 peeled (h_0 = relu(xw_0)); out_{T-1} in epilogue.
// ---------------------------------------------------------------------------
__global__ __launch_bounds__(512, 1)
void rnn_scan_kernel(const float* __restrict__ xw, const float* __restrict__ W_hh,
                     const float* __restrict__ W_out, const float* __restrict__ b_out,
                     float* __restrict__ out)
{
    const int tid = threadIdx.x;
    const int jb  = tid & 31;
    const int kb  = tid >> 5;                 // 0..15
    const int r   = blockIdx.x;               // batch row

    __shared__ __align__(16) float hs[H_];
    __shared__ __align__(16) float part[16 * 256];
    __shared__ __align__(16) float opart[16 * 64];

    // register-resident W_hh tile: lane holds W_hh[jb*8+a][kb*16+c]
    float4 wa[8][4];
#pragma unroll
    for (int a = 0; a < 8; ++a) {
        const float* wrow = W_hh + (size_t)(jb * 8 + a) * H_ + kb * 16;
#pragma unroll
        for (int c4 = 0; c4 < 4; ++c4)
            wa[a][c4] = reinterpret_cast<const float4*>(wrow)[c4];
    }
    // register-resident W_out tile: lane holds W_out[jb*2+d][kb*16+c]
    float4 wo[2][4];
#pragma unroll
    for (int d = 0; d < 2; ++d) {
        const float* wrow = W_out + (size_t)(jb * 2 + d) * H_ + kb * 16;
#pragma unroll
        for (int c4 = 0; c4 < 4; ++c4)
            wo[d][c4] = reinterpret_cast<const float4*>(wrow)[c4];
    }

    const float* xwrow = xw + (size_t)r * T_ * H_;
    float* outrow = out + (size_t)r * T_ * O_;
    const float bo = (tid >= 256 && tid < 320) ? b_out[tid - 256] : 0.f;

    // ---- iteration 0: h_0 = relu(xw_0), no fmacs ----
    float xwreg = 0.f, xwn1 = 0.f, xwn2 = 0.f;
    if (tid < 256) {
        hs[tid] = fmaxf(xwrow[tid], 0.f);
        xwreg = xwrow[(size_t)1 * H_ + tid];  // for t=1
        xwn1  = xwrow[(size_t)2 * H_ + tid];  // for t=2
    }
    __syncthreads();

    float4 hr[4];                             // h_{t-1}[kb*16 .. +16)
    {
        const float4* hs4 = reinterpret_cast<const float4*>(hs);
#pragma unroll
        for (int c4 = 0; c4 < 4; ++c4) hr[c4] = hs4[kb * 4 + c4];
    }

#pragma unroll 1
    for (int t = 1; t < T_; ++t) {
        // issue xw prefetch for t+2 (clamped)
        if (tid < 256) {
            const int tt = (t + 2 < T_) ? (t + 2) : (T_ - 1);
            xwn2 = xwrow[(size_t)tt * H_ + tid];
        }

        // --- phase 1: recurrence + out-proj fmacs (all waves) ---
        float acc[8];
#pragma unroll
        for (int a = 0; a < 8; ++a) acc[a] = 0.f;
        float oa0 = 0.f, oa1 = 0.f;
#pragma unroll
        for (int c4 = 0; c4 < 4; ++c4) {
            const float4 hv = hr[c4];
#pragma unroll
            for (int a = 0; a < 8; ++a) {
                const float4 wv = wa[a][c4];
                acc[a] = fmaf(hv.x, wv.x, acc[a]);
                acc[a] = fmaf(hv.y, wv.y, acc[a]);
                acc[a] = fmaf(hv.z, wv.z, acc[a]);
                acc[a] = fmaf(hv.w, wv.w, acc[a]);
            }
            const float4 w0 = wo[0][c4], w1 = wo[1][c4];
            oa0 = fmaf(hv.x, w0.x, oa0); oa0 = fmaf(hv.y, w0.y, oa0);
            oa0 = fmaf(hv.z, w0.z, oa0); oa0 = fmaf(hv.w, w0.w, oa0);
            oa1 = fmaf(hv.x, w1.x, oa1); oa1 = fmaf(hv.y, w1.y, oa1);
            oa1 = fmaf(hv.z, w1.z, oa1); oa1 = fmaf(hv.w, w1.w, oa1);
        }
        {   // swizzled partial writes (conflict-minimal)
            float4* p4 = reinterpret_cast<float4*>(part);
            p4[kb * 64 + ((jb * 2 + 0) ^ kb)] = make_float4(acc[0], acc[1], acc[2], acc[3]);
            p4[kb * 64 + ((jb * 2 + 1) ^ kb)] = make_float4(acc[4], acc[5], acc[6], acc[7]);
            reinterpret_cast<float2*>(opart)[kb * 32 + jb] = make_float2(oa0, oa1);
        }
        __syncthreads();                      // (1) partials visible

        // --- phase 2: concurrent reductions ---
        if (tid < 256) {                      // waves 0-3: h_t
            const int q = tid >> 2, m = tid & 3;
            float s = 0.f;
#pragma unroll
            for (int g = 0; g < 16; ++g)
                s += part[g * 256 + (((q ^ g) << 2) | m)];
            s += xwreg;
            hs[tid] = (s > 0.f) ? s : 0.f;
            xwreg = xwn1; xwn1 = xwn2;        // shift prefetch pipeline
        } else if (tid < 320) {               // wave 4: out_{t-1}
            const int to = tid - 256;
            float s = 0.f;
#pragma unroll
            for (int g = 0; g < 16; ++g) s += opart[g * 64 + to];
            outrow[(size_t)(t - 1) * O_ + to] = s + bo;
        }
        __syncthreads();                      // (2) h_t visible

        {   // hr <- h_t (serves next recurrence AND next out-proj)
            const float4* hs4 = reinterpret_cast<const float4*>(hs);
#pragma unroll
            for (int c4 = 0; c4 < 4; ++c4) hr[c4] = hs4[kb * 4 + c4];
        }
    }

    // ---- epilogue: out_{T-1} from hr = h_{T-1} ----
    {
        float oa0 = 0.f, oa1 = 0.f;
#pragma unroll
        for (int c4 = 0; c4 < 4; ++c4) {
            const float4 hv = hr[c4];
            const float4 w0 = wo[0][c4], w1 = wo[1][c4];
            oa0 = fmaf(hv.x, w0.x, oa0); oa0 = fmaf(hv.y, w0.y, oa0);
            oa0 = fmaf(hv.z, w0.z, oa0); oa0 = fmaf(hv.w, w0.w, oa0);
            oa1 = fmaf(hv.x, w1.x, oa1); oa1 = fmaf(hv.y, w1.y, oa1);
            oa1 = fmaf(hv.z, w1.z, oa1); oa1 = fmaf(hv.w, w1.w, oa1);
        }
        reinterpret_cast<float2*>(opart)[kb * 32 + jb] = make_float2(oa0, oa1);
        __syncthreads();
        if (tid >= 256 && tid < 320) {
            const int to = tid - 256;
            float s = 0.f;
#pragma unroll
            for (int g = 0; g < 16; ++g) s += opart[g * 64 + to];
            outrow[(size_t)(T_ - 1) * O_ + to] = s + bo;
        }
    }
}

// ---------------------------------------------------------------------------
extern "C" void kernel_launch(void* const* d_in, const int* in_sizes, int n_in,
                              void* d_out, int out_size, void* d_ws, size_t ws_size,
                              hipStream_t stream)
{
    (void)in_sizes; (void)n_in; (void)out_size; (void)ws_size;
    const float* x     = (const float*)d_in[0];   // [B,T,I]
    const float* W_xh  = (const float*)d_in[1];   // [H,I]
    const float* W_hh  = (const float*)d_in[2];   // [H,H]
    const float* b_h   = (const float*)d_in[3];   // [H]
    const float* W_out = (const float*)d_in[4];   // [O,H]
    const float* b_out = (const float*)d_in[5];   // [O]
    float* out = (float*)d_out;                   // [B,T,O]
    float* xw  = (float*)d_ws;                    // [B*T*H] fp32 = 128 MiB scratch

    xw_gemm_kernel<<<512, 256, 0, stream>>>(x, W_xh, b_h, xw);
    rnn_scan_kernel<<<128, 512, 0, stream>>>(xw, W_hh, W_out, b_out, out);
}